// Round 10
// baseline (514.801 us; speedup 1.0000x reference)
//
#include <hip/hip_runtime.h>
#include <hip/hip_fp16.h>

typedef unsigned int u32;
typedef unsigned short u16;

#define N_NODES  100000
#define N_EDGES  1600000
#define N_GRAPHS 128
#define NBG      6250       // gemm blocks (16 rows each)
#define NBE      6250       // 1600000/256 deg blocks
#define NBN      391        // ceil(100000/256) bhist blocks
#define NPB1     782        // nodes per pool1 block (128*782 >= 100000)

__device__ __forceinline__ float h2f(u16 h) { return __half2float(__ushort_as_half(h)); }
__device__ __forceinline__ u16 f2h(float f) { return __half_as_ushort(__float2half_rn(f)); }

// ---- fused: gemm (t1h = fp16(x@W1), unscaled) + degree histogram + per-graph histogram ----
__global__ __launch_bounds__(256) void k_fused(const float* __restrict__ x, const float* __restrict__ W1,
                                               u16* __restrict__ t1h,
                                               const int* __restrict__ dst, int* __restrict__ deg,
                                               const int* __restrict__ batch, int* __restrict__ bhist) {
    int b = blockIdx.x, t = threadIdx.x;
    if (b < NBG) {
        __shared__ float w[128 * 16];
        __shared__ float xs[16][132];
        {
            const float4* wv = (const float4*)W1;
            ((float4*)w)[t * 2]     = wv[t * 2];
            ((float4*)w)[t * 2 + 1] = wv[t * 2 + 1];
        }
        int base = b * 16;
        {
            const float4* xv = (const float4*)(x + (size_t)base * 128);
            #pragma unroll
            for (int q = 0; q < 2; ++q) {
                int i4 = t * 2 + q;
                float4 v = xv[i4];
                int idx = i4 * 4;
                *((float4*)&xs[idx >> 7][idx & 127]) = v;
            }
        }
        __syncthreads();
        int nl = t >> 4, j = t & 15;
        int n = base + nl;
        const float4* xr = (const float4*)&xs[nl][0];
        float acc = 0.f;
        #pragma unroll
        for (int k4 = 0; k4 < 32; ++k4) {
            float4 v = xr[k4];
            acc += v.x * w[(k4 * 4 + 0) * 16 + j];
            acc += v.y * w[(k4 * 4 + 1) * 16 + j];
            acc += v.z * w[(k4 * 4 + 2) * 16 + j];
            acc += v.w * w[(k4 * 4 + 3) * 16 + j];
        }
        t1h[n * 16 + j] = f2h(acc);
    } else if (b < NBG + NBE) {
        int e = (b - NBG) * 256 + t;            // exact
        atomicAdd(&deg[dst[e]], 1);
    } else {
        __shared__ int bh[N_GRAPHS];
        if (t < N_GRAPHS) bh[t] = 0;
        __syncthreads();
        int n = (b - NBG - NBE) * 256 + t;
        if (n < N_NODES) atomicAdd(&bh[batch[n]], 1);
        __syncthreads();
        if (t < N_GRAPHS && bh[t] > 0) atomicAdd(&bhist[t], bh[t]);
    }
}

// ---- scale in place: hs1 = fp16(dinv * t1); store dinv ----
__global__ __launch_bounds__(256) void k_scale(u16* __restrict__ t1h, const int* __restrict__ deg,
                                               float* __restrict__ dinv) {
    int gid = blockIdx.x * 256 + threadIdx.x;   // 1563 blocks
    int n = gid >> 2, q = gid & 3;
    if (n >= N_NODES) return;
    float dv = rsqrtf((float)(deg[n] + 1));
    if (q == 0) dinv[n] = dv;
    int base = n * 4 + q;
    ushort4 v = ((const ushort4*)t1h)[base];
    v.x = f2h(dv * h2f(v.x)); v.y = f2h(dv * h2f(v.y));
    v.z = f2h(dv * h2f(v.z)); v.w = f2h(dv * h2f(v.w));
    ((ushort4*)t1h)[base] = v;
}

// ---- propagation: 8 lanes/edge, one packed-fp16 HW atomic each into L2-resident table ----
__global__ __launch_bounds__(256) void k_prop(const int* __restrict__ src, const int* __restrict__ dst,
                                              const __half2* __restrict__ hs, __half2* __restrict__ pacc) {
    int gid = blockIdx.x * 256 + threadIdx.x;   // 12,800,000 exactly (50000 blocks)
    int e = gid >> 3, h = gid & 7;
    int s = src[e], d = dst[e];
    __half2 v = hs[s * 8 + h];
    u32 bits; __builtin_memcpy(&bits, &v, 4);
    if (bits) unsafeAtomicAdd(&pacc[d * 8 + h], v);   // global_atomic_pk_add_f16
}

// ---- epilogue 1: h1 = relu(dinv*(pacc+hs1) + b1); hs2 = fp16(dinv*h1); pacc = 0 ----
__global__ __launch_bounds__(256) void k_epi1(u16* __restrict__ pacc, const u16* __restrict__ hs1,
                                              const float* __restrict__ dinv, const float* __restrict__ b1,
                                              u16* __restrict__ hs2) {
    int gid = blockIdx.x * 256 + threadIdx.x;   // 1563 blocks
    int n = gid >> 2, q = gid & 3;
    if (n >= N_NODES) return;
    int base = n * 4 + q;
    ushort4 pv = ((const ushort4*)pacc)[base];
    ushort4 hv = ((const ushort4*)hs1)[base];
    float4 bb = ((const float4*)b1)[q];
    float dv = dinv[n];
    float h0 = fmaxf(dv * (h2f(pv.x) + h2f(hv.x)) + bb.x, 0.f);
    float h1 = fmaxf(dv * (h2f(pv.y) + h2f(hv.y)) + bb.y, 0.f);
    float h2 = fmaxf(dv * (h2f(pv.z) + h2f(hv.z)) + bb.z, 0.f);
    float h3 = fmaxf(dv * (h2f(pv.w) + h2f(hv.w)) + bb.w, 0.f);
    ushort4 o;
    o.x = f2h(dv * h0); o.y = f2h(dv * h1); o.z = f2h(dv * h2); o.w = f2h(dv * h3);
    ((ushort4*)hs2)[base] = o;
    ushort4 z = {0, 0, 0, 0};
    ((ushort4*)pacc)[base] = z;                  // re-zero for layer-2 accumulation
}

// ---- pool stage 1: 128 blocks; private 128x128 f32 LDS table; no atomics (thread owns column) ----
__global__ __launch_bounds__(128) void k_pool1(const u16* __restrict__ pacc, const u16* __restrict__ hs2,
                                               const float* __restrict__ dinv,
                                               const float* __restrict__ W2, const float* __restrict__ b2,
                                               const int* __restrict__ batch, float* __restrict__ staging) {
    __shared__ float accT[N_GRAPHS * 128];       // 64 KB
    __shared__ float w2s[16 * 128];              // 8 KB
    __shared__ float b2s[128];
    __shared__ float qbuf[8][16];
    __shared__ int   gbuf[8];
    int b = blockIdx.x, j = threadIdx.x;         // 128 threads
    {
        const float4* wv = (const float4*)W2;
        #pragma unroll
        for (int q = 0; q < 4; ++q) ((float4*)w2s)[j * 4 + q] = wv[j * 4 + q];
        b2s[j] = b2[j];
    }
    for (int i = 0; i < N_GRAPHS; ++i) accT[i * 128 + j] = 0.f;
    int base = b * NPB1;
    int lim = base + NPB1; if (lim > N_NODES) lim = N_NODES;
    for (int ch = 0; ch < NPB1; ch += 8) {
        __syncthreads();
        {   // load 8 nodes' q2 rows: thread j -> node j>>4, feat j&15
            int nl = j >> 4, k = j & 15;
            int idx = base + ch + nl;
            if (idx < lim) {
                float dv = dinv[idx];
                qbuf[nl][k] = dv * (h2f(pacc[idx * 16 + k]) + h2f(hs2[idx * 16 + k]));
                if (k == 0) gbuf[nl] = batch[idx];
            } else if (k == 0) gbuf[nl] = -1;
        }
        __syncthreads();
        #pragma unroll
        for (int nl = 0; nl < 8; ++nl) {
            int g = gbuf[nl];
            if (g < 0) break;
            float a = b2s[j];
            #pragma unroll
            for (int k = 0; k < 16; ++k) a += qbuf[nl][k] * w2s[k * 128 + j];
            accT[g * 128 + j] += fmaxf(a, 0.f);
        }
    }
    __syncthreads();
    float* sp = staging + (size_t)b * (N_GRAPHS * 128);
    for (int g = 0; g < N_GRAPHS; ++g) sp[g * 128 + j] = accT[g * 128 + j];
}

// ---- pool stage 2 + MLP head + log_softmax: 128 blocks (one per graph) x 128 threads ----
__global__ __launch_bounds__(128) void k_pool2head(const float* __restrict__ staging,
                                                   const int* __restrict__ bhist,
                                                   const float* __restrict__ LW1, const float* __restrict__ Lb1,
                                                   const float* __restrict__ LW2, const float* __restrict__ Lb2,
                                                   float* __restrict__ out) {
    __shared__ float srow[128];
    __shared__ float z1s[128];
    __shared__ float zz[2];
    int g = blockIdx.x, t = threadIdx.x;
    float s = 0.f;
    const float* p = staging + g * 128 + t;
    #pragma unroll 4
    for (int b = 0; b < 128; ++b) s += p[(size_t)b * (N_GRAPHS * 128)];
    float rc = 1.0f / fmaxf((float)bhist[g], 1.0f);
    srow[t] = s * rc;
    __syncthreads();
    float a = Lb1[t];
    for (int k = 0; k < 128; ++k) a += srow[k] * LW1[k * 128 + t];
    z1s[t] = fmaxf(a, 0.f);
    __syncthreads();
    if (t < 2) {
        float z = Lb2[t];
        for (int jj = 0; jj < 128; ++jj) z += z1s[jj] * LW2[jj * 2 + t];
        zz[t] = z;
    }
    __syncthreads();
    if (t < 2) {
        float m = fmaxf(zz[0], zz[1]);
        float lse = m + logf(expf(zz[0] - m) + expf(zz[1] - m));
        out[g * 2 + t] = zz[t] - lse;
    }
}

extern "C" void kernel_launch(void* const* d_in, const int* in_sizes, int n_in,
                              void* d_out, int out_size, void* d_ws, size_t ws_size,
                              hipStream_t stream) {
    const float* x   = (const float*)d_in[0];
    const int* ei    = (const int*)d_in[1];
    const int* batch = (const int*)d_in[2];
    const float* W1  = (const float*)d_in[3];
    const float* b1  = (const float*)d_in[4];
    const float* W2  = (const float*)d_in[5];
    const float* b2  = (const float*)d_in[6];
    const float* LW1 = (const float*)d_in[7];
    const float* Lb1 = (const float*)d_in[8];
    const float* LW2 = (const float*)d_in[9];
    const float* Lb2 = (const float*)d_in[10];
    const int* src = ei;
    const int* dst = ei + N_EDGES;

    char* ws = (char*)d_ws;
    int*   bhist   = (int*)(ws);                  // 512 B
    int*   deg     = (int*)(ws + 512);            // 400000 B
    u16*   paccH   = (u16*)(ws + 400512);         // 3200000 B (fp16 accum, L2-resident)
    // ---- memset covers [0, 3600512) ----
    float* dinv    = (float*)(ws + 3600512);      // 400000 B
    u16*   hs1     = (u16*)(ws + 4000512);        // 3200000 B (t1h then scaled in place)
    u16*   hs2     = (u16*)(ws + 7200512);        // 3200000 B
    float* staging = (float*)(ws + 10400512);     // 8388608 B (128 x 64KB)
    float* out     = (float*)d_out;

    (void)hipMemsetAsync(ws, 0, 3600512, stream);

    k_fused    <<<NBG + NBE + NBN, 256, 0, stream>>>(x, W1, hs1, dst, deg, batch, bhist);
    k_scale    <<<1563,            256, 0, stream>>>(hs1, deg, dinv);
    k_prop     <<<50000,           256, 0, stream>>>(src, dst, (const __half2*)hs1, (__half2*)paccH);
    k_epi1     <<<1563,            256, 0, stream>>>(paccH, hs1, dinv, b1, hs2);
    k_prop     <<<50000,           256, 0, stream>>>(src, dst, (const __half2*)hs2, (__half2*)paccH);
    k_pool1    <<<128,             128, 0, stream>>>(paccH, hs2, dinv, W2, b2, batch, staging);
    k_pool2head<<<128,             128, 0, stream>>>(staging, bhist, LW1, Lb1, LW2, Lb2, out);
}

// Round 11
// 391.488 us; speedup vs baseline: 1.3150x; 1.3150x over previous
//
#include <hip/hip_runtime.h>
#include <hip/hip_fp16.h>

typedef unsigned int u32;
typedef unsigned short u16;

#define N_NODES  100000
#define N_EDGES  1600000
#define N_GRAPHS 128
#define NBG      6250       // gemm blocks (16 rows each)
#define NBE      6250       // deg-hist blocks (1600000/256)
#define NBN      391        // node blocks (ceil(100000/256))
#define NHIST    (N_GRAPHS * NBN)   // 50048
#define NBS      196        // scan blocks (196*256 = 50176 >= 50048)

__device__ __forceinline__ float h2f(u16 h) { return __half2float(__ushort_as_half(h)); }
__device__ __forceinline__ u16 f2h(float f) { return __half_as_ushort(__float2half_rn(f)); }

// ---- fused: gemm (t1h = fp16(x@W1), unscaled) + degree histogram + per-block graph histograms ----
__global__ __launch_bounds__(256) void k_fused(const float* __restrict__ x, const float* __restrict__ W1,
                                               u16* __restrict__ t1h,
                                               const int* __restrict__ dst, int* __restrict__ deg,
                                               const int* __restrict__ batch, int* __restrict__ nhist) {
    int b = blockIdx.x, t = threadIdx.x;
    if (b < NBG) {
        __shared__ float w[128 * 16];
        __shared__ float xs[16][132];
        {
            const float4* wv = (const float4*)W1;
            ((float4*)w)[t * 2]     = wv[t * 2];
            ((float4*)w)[t * 2 + 1] = wv[t * 2 + 1];
        }
        int base = b * 16;
        {
            const float4* xv = (const float4*)(x + (size_t)base * 128);
            #pragma unroll
            for (int q = 0; q < 2; ++q) {
                int i4 = t * 2 + q;
                float4 v = xv[i4];
                int idx = i4 * 4;
                *((float4*)&xs[idx >> 7][idx & 127]) = v;
            }
        }
        __syncthreads();
        int nl = t >> 4, j = t & 15;
        int n = base + nl;
        const float4* xr = (const float4*)&xs[nl][0];
        float acc = 0.f;
        #pragma unroll
        for (int k4 = 0; k4 < 32; ++k4) {
            float4 v = xr[k4];
            acc += v.x * w[(k4 * 4 + 0) * 16 + j];
            acc += v.y * w[(k4 * 4 + 1) * 16 + j];
            acc += v.z * w[(k4 * 4 + 2) * 16 + j];
            acc += v.w * w[(k4 * 4 + 3) * 16 + j];
        }
        t1h[n * 16 + j] = f2h(acc);
    } else if (b < NBG + NBE) {
        int e = (b - NBG) * 256 + t;            // exact
        atomicAdd(&deg[dst[e]], 1);
    } else {
        __shared__ int bh[N_GRAPHS];
        int nb = b - NBG - NBE;                 // [0, 391)
        if (t < N_GRAPHS) bh[t] = 0;
        __syncthreads();
        int n = nb * 256 + t;
        if (n < N_NODES) atomicAdd(&bh[batch[n]], 1);
        __syncthreads();
        if (t < N_GRAPHS) nhist[t * NBN + nb] = bh[t];   // dense per-block histogram, no global atomics
    }
}

// ---- scan stage 1: 256-elem tile sums of nhist[50048] ----
__global__ __launch_bounds__(256) void k_scanN1(const int* __restrict__ nhist, int* __restrict__ nsum) {
    __shared__ int sh[256];
    int t = threadIdx.x, i = blockIdx.x * 256 + t;
    sh[t] = (i < NHIST) ? nhist[i] : 0;
    __syncthreads();
    for (int off = 128; off > 0; off >>= 1) {
        if (t < off) sh[t] += sh[t + off];
        __syncthreads();
    }
    if (t == 0) nsum[blockIdx.x] = sh[0];
}

// ---- scan stage 2: 1 block scans nsum[196] ----
__global__ __launch_bounds__(256) void k_scanN2(int* __restrict__ nsum) {
    __shared__ int s1[256], s2[256];
    int t = threadIdx.x;
    int v = (t < NBS) ? nsum[t] : 0;
    s1[t] = v; __syncthreads();
    int* pa = s1; int* pb = s2;
    for (int off = 1; off < 256; off <<= 1) {
        int x = pa[t];
        if (t >= off) x += pa[t - off];
        pb[t] = x; __syncthreads();
        int* tmp = pa; pa = pb; pb = tmp;
    }
    if (t < NBS) nsum[t] = pa[t] - v;           // exclusive
}

// ---- scan stage 3: in-place exclusive scan of nhist + block offset ----
__global__ __launch_bounds__(256) void k_scanN3(int* __restrict__ nhist, const int* __restrict__ nsum) {
    __shared__ int s1[256], s2[256];
    int t = threadIdx.x, i = blockIdx.x * 256 + t;
    int v = (i < NHIST) ? nhist[i] : 0;
    s1[t] = v; __syncthreads();
    int* pa = s1; int* pb = s2;
    for (int off = 1; off < 256; off <<= 1) {
        int x = pa[t];
        if (t >= off) x += pa[t - off];
        pb[t] = x; __syncthreads();
        int* tmp = pa; pa = pb; pb = tmp;
    }
    if (i < NHIST) nhist[i] = pa[t] - v + nsum[blockIdx.x];
}

// ---- scatter nodes by graph using scanned cursors (LDS atomics only) ----
__global__ __launch_bounds__(256) void k_scatterN(const int* __restrict__ batch, const int* __restrict__ nhistS,
                                                  int* __restrict__ nodeS) {
    __shared__ int cur[N_GRAPHS];
    int b = blockIdx.x, t = threadIdx.x;        // 391 blocks
    if (t < N_GRAPHS) cur[t] = nhistS[t * NBN + b];
    __syncthreads();
    int n = b * 256 + t;
    if (n < N_NODES) {
        int pos = atomicAdd(&cur[batch[n]], 1);
        nodeS[pos] = n;
    }
}

// ---- scale in place: hs1 = fp16(dinv * t1); store dinv ----
__global__ __launch_bounds__(256) void k_scale(u16* __restrict__ t1h, const int* __restrict__ deg,
                                               float* __restrict__ dinv) {
    int gid = blockIdx.x * 256 + threadIdx.x;   // 1563 blocks
    int n = gid >> 2, q = gid & 3;
    if (n >= N_NODES) return;
    float dv = rsqrtf((float)(deg[n] + 1));
    if (q == 0) dinv[n] = dv;
    int base = n * 4 + q;
    ushort4 v = ((const ushort4*)t1h)[base];
    v.x = f2h(dv * h2f(v.x)); v.y = f2h(dv * h2f(v.y));
    v.z = f2h(dv * h2f(v.z)); v.w = f2h(dv * h2f(v.w));
    ((ushort4*)t1h)[base] = v;
}

// ---- propagation: 8 lanes/edge, one packed-fp16 HW atomic each into L2-resident table ----
__global__ __launch_bounds__(256) void k_prop(const int* __restrict__ src, const int* __restrict__ dst,
                                              const __half2* __restrict__ hs, __half2* __restrict__ pacc) {
    int gid = blockIdx.x * 256 + threadIdx.x;   // 12,800,000 exactly (50000 blocks)
    int e = gid >> 3, h = gid & 7;
    int s = src[e], d = dst[e];
    __half2 v = hs[s * 8 + h];
    u32 bits; __builtin_memcpy(&bits, &v, 4);
    if (bits) unsafeAtomicAdd(&pacc[d * 8 + h], v);   // global_atomic_pk_add_f16
}

// ---- epilogue 1: h1 = relu(dinv*(pacc+hs1) + b1); hs2 = fp16(dinv*h1); pacc = 0 ----
__global__ __launch_bounds__(256) void k_epi1(u16* __restrict__ pacc, const u16* __restrict__ hs1,
                                              const float* __restrict__ dinv, const float* __restrict__ b1,
                                              u16* __restrict__ hs2) {
    int gid = blockIdx.x * 256 + threadIdx.x;   // 1563 blocks
    int n = gid >> 2, q = gid & 3;
    if (n >= N_NODES) return;
    int base = n * 4 + q;
    ushort4 pv = ((const ushort4*)pacc)[base];
    ushort4 hv = ((const ushort4*)hs1)[base];
    float4 bb = ((const float4*)b1)[q];
    float dv = dinv[n];
    float h0 = fmaxf(dv * (h2f(pv.x) + h2f(hv.x)) + bb.x, 0.f);
    float h1 = fmaxf(dv * (h2f(pv.y) + h2f(hv.y)) + bb.y, 0.f);
    float h2 = fmaxf(dv * (h2f(pv.z) + h2f(hv.z)) + bb.z, 0.f);
    float h3 = fmaxf(dv * (h2f(pv.w) + h2f(hv.w)) + bb.w, 0.f);
    ushort4 o;
    o.x = f2h(dv * h0); o.y = f2h(dv * h1); o.z = f2h(dv * h2); o.w = f2h(dv * h3);
    ((ushort4*)hs2)[base] = o;
    ushort4 z = {0, 0, 0, 0};
    ((ushort4*)pacc)[base] = z;                  // re-zero for layer-2 accumulation
}

// ---- pooling: 64 sorted nodes/block, inline q2 = dinv*(pacc+hs2), segment-accumulate ----
__global__ __launch_bounds__(256) void k_pool(const u16* __restrict__ pacc, const u16* __restrict__ hs2,
                                              const float* __restrict__ dinv,
                                              const float* __restrict__ W2, const float* __restrict__ b2,
                                              const int* __restrict__ nodeS, const int* __restrict__ batch,
                                              float* __restrict__ sums) {
    __shared__ float w[16 * 128];
    __shared__ float bsh[128];
    __shared__ float rows[64][16];
    __shared__ int   gid[64];
    int t = threadIdx.x;
    {
        const float4* wv = (const float4*)W2;
        ((float4*)w)[t * 2]     = wv[t * 2];
        ((float4*)w)[t * 2 + 1] = wv[t * 2 + 1];
    }
    if (t < 128) bsh[t] = b2[t];
    int base = blockIdx.x * 64;                 // 1563 blocks
    {
        int which = t >> 2, qq = t & 3;
        int idx = base + which;
        if (idx < N_NODES) {
            int node = nodeS[idx];
            if (qq == 0) gid[which] = batch[node];
            float dv = dinv[node];
            ushort4 pv = ((const ushort4*)pacc)[node * 4 + qq];
            ushort4 hv = ((const ushort4*)hs2)[node * 4 + qq];
            rows[which][qq * 4 + 0] = dv * (h2f(pv.x) + h2f(hv.x));
            rows[which][qq * 4 + 1] = dv * (h2f(pv.y) + h2f(hv.y));
            rows[which][qq * 4 + 2] = dv * (h2f(pv.z) + h2f(hv.z));
            rows[which][qq * 4 + 3] = dv * (h2f(pv.w) + h2f(hv.w));
        }
    }
    __syncthreads();
    int half = t >> 7, j = t & 127;
    float acc = 0.f;
    int curg = -1;
    for (int it = 0; it < 32; ++it) {
        int wh = half * 32 + it;
        int idx = base + wh;
        if (idx >= N_NODES) break;
        int g = gid[wh];
        if (g != curg) {
            if (curg >= 0) atomicAdd(&sums[curg * 128 + j], acc);
            curg = g; acc = 0.f;
        }
        float a = bsh[j];
        #pragma unroll
        for (int kk = 0; kk < 16; ++kk) a += rows[wh][kk] * w[kk * 128 + j];
        acc += fmaxf(a, 0.f);
    }
    if (curg >= 0) atomicAdd(&sums[curg * 128 + j], acc);
}

// ---- fused MLP head + log_softmax (graph counts from scanned nhist) ----
__global__ __launch_bounds__(128) void k_head(const float* __restrict__ sums, const int* __restrict__ nhistS,
                                              const float* __restrict__ LW1, const float* __restrict__ Lb1,
                                              const float* __restrict__ LW2, const float* __restrict__ Lb2,
                                              float* __restrict__ out) {
    __shared__ float srow[128];
    __shared__ float z1s[128];
    __shared__ float zz[2];
    int g = blockIdx.x, t = threadIdx.x;
    int lo = nhistS[g * NBN];
    int hi = (g == N_GRAPHS - 1) ? N_NODES : nhistS[(g + 1) * NBN];
    float rc = 1.0f / fmaxf((float)(hi - lo), 1.0f);
    srow[t] = sums[g * 128 + t] * rc;
    __syncthreads();
    float a = Lb1[t];
    for (int k = 0; k < 128; ++k) a += srow[k] * LW1[k * 128 + t];
    z1s[t] = fmaxf(a, 0.f);
    __syncthreads();
    if (t < 2) {
        float z = Lb2[t];
        for (int jj = 0; jj < 128; ++jj) z += z1s[jj] * LW2[jj * 2 + t];
        zz[t] = z;
    }
    __syncthreads();
    if (t < 2) {
        float m = fmaxf(zz[0], zz[1]);
        float lse = m + logf(expf(zz[0] - m) + expf(zz[1] - m));
        out[g * 2 + t] = zz[t] - lse;
    }
}

extern "C" void kernel_launch(void* const* d_in, const int* in_sizes, int n_in,
                              void* d_out, int out_size, void* d_ws, size_t ws_size,
                              hipStream_t stream) {
    const float* x   = (const float*)d_in[0];
    const int* ei    = (const int*)d_in[1];
    const int* batch = (const int*)d_in[2];
    const float* W1  = (const float*)d_in[3];
    const float* b1  = (const float*)d_in[4];
    const float* W2  = (const float*)d_in[5];
    const float* b2  = (const float*)d_in[6];
    const float* LW1 = (const float*)d_in[7];
    const float* Lb1 = (const float*)d_in[8];
    const float* LW2 = (const float*)d_in[9];
    const float* Lb2 = (const float*)d_in[10];
    const int* src = ei;
    const int* dst = ei + N_EDGES;

    char* ws = (char*)d_ws;
    float* sums  = (float*)(ws);                  // 65536 B
    int*   deg   = (int*)(ws + 65536);            // 400000 B
    u16*   paccH = (u16*)(ws + 465536);           // 3200000 B (fp16 accum, L2-resident)
    // ---- memset covers [0, 3665536) ----
    int*   nhist = (int*)(ws + 3665536);          // 200192 B (50048 ints; scanned in place)
    int*   nsum  = (int*)(ws + 3865728);          // 1024 B
    float* dinv  = (float*)(ws + 3866752);        // 400000 B
    int*   nodeS = (int*)(ws + 4266752);          // 400000 B
    u16*   hs1   = (u16*)(ws + 4666752);          // 3200000 B (t1h, scaled in place)
    u16*   hs2   = (u16*)(ws + 7866752);          // 3200000 B
    float* out   = (float*)d_out;

    (void)hipMemsetAsync(ws, 0, 3665536, stream);

    k_fused   <<<NBG + NBE + NBN, 256, 0, stream>>>(x, W1, hs1, dst, deg, batch, nhist);
    k_scanN1  <<<NBS,             256, 0, stream>>>(nhist, nsum);
    k_scanN2  <<<1,               256, 0, stream>>>(nsum);
    k_scanN3  <<<NBS,             256, 0, stream>>>(nhist, nsum);
    k_scatterN<<<NBN,             256, 0, stream>>>(batch, nhist, nodeS);
    k_scale   <<<1563,            256, 0, stream>>>(hs1, deg, dinv);
    k_prop    <<<50000,           256, 0, stream>>>(src, dst, (const __half2*)hs1, (__half2*)paccH);
    k_epi1    <<<1563,            256, 0, stream>>>(paccH, hs1, dinv, b1, hs2);
    k_prop    <<<50000,           256, 0, stream>>>(src, dst, (const __half2*)hs2, (__half2*)paccH);
    k_pool    <<<1563,            256, 0, stream>>>(paccH, hs2, dinv, W2, b2, nodeS, batch, sums);
    k_head    <<<128,             128, 0, stream>>>(sums, nhist, LW1, Lb1, LW2, Lb2, out);
}